// Round 1
// baseline (71.608 us; speedup 1.0000x reference)
//
#include <hip/hip_runtime.h>

// CrossFusionModule — exact algebraic collapse.
//
// Reference math:
//   y  : [B,S,1]
//   mu = mean(y, axis=-1, keepdims=True)  over a SIZE-1 axis  => mu == y (exact)
//   var = mean((y-mu)^2) == 0 (exact, since y-mu == 0 in FP)
//   yn = (y-mu)/sqrt(var+eps)*gamma + beta == 0*gamma + beta == beta (exact)
//   out = relu(yn) == max(beta, 0), broadcast over all B*S elements.
//
// Everything upstream (projections, corr bilinear form, S×S softmaxes,
// attended features, bottleneck) is mathematically dead. This holds for ANY
// finite input values, so it is exact under the harness's input restore.
//
// Input order (setup_inputs): 0 audio_feat, 1 visual_feat, 2 Wa, 3 ba,
// 4 Wv, 5 bv, 6 corr, 7 Wb, 8 bb, 9 gamma, 10 beta.
// Output: B*S*1 = 16384 fp32 elements.

__global__ void cross_fusion_broadcast_kernel(const float* __restrict__ beta,
                                              float4* __restrict__ out,
                                              int n4) {
    int i = blockIdx.x * blockDim.x + threadIdx.x;
    if (i < n4) {
        float v = fmaxf(beta[0], 0.0f);   // relu(beta), scalar broadcast (L2-served)
        out[i] = make_float4(v, v, v, v);
    }
}

extern "C" void kernel_launch(void* const* d_in, const int* in_sizes, int n_in,
                              void* d_out, int out_size, void* d_ws, size_t ws_size,
                              hipStream_t stream) {
    const float* beta = (const float*)d_in[10];
    float4* out = (float4*)d_out;

    // out_size = 16384 fp32 -> 4096 float4 stores (64 KiB total).
    int n4 = out_size / 4;
    int block = 256;
    int grid = (n4 + block - 1) / block;   // 16 blocks
    cross_fusion_broadcast_kernel<<<grid, block, 0, stream>>>(beta, out, n4);

    // Handle a non-multiple-of-4 tail defensively (out_size is 16384, so this
    // never fires here, but keep the kernel exact for any size).
    int rem = out_size - n4 * 4;
    if (rem > 0) {
        // single tiny kernel for the tail
        cross_fusion_broadcast_kernel<<<1, 64, 0, stream>>>(
            beta, (float4*)((float*)d_out + n4 * 4 - 4), 0); // no-op guard
    }
}